// Round 9
// baseline (276.280 us; speedup 1.0000x reference)
//
#include <hip/hip_runtime.h>

#define NB 8
#define SEQ 2048
#define DIM 768

typedef _Float16 f16;
typedef _Float16 f16x8 __attribute__((ext_vector_type(8)));
typedef _Float16 f16x4 __attribute__((ext_vector_type(4)));
typedef short s16x8 __attribute__((ext_vector_type(8)));
typedef unsigned short u16x4 __attribute__((ext_vector_type(4)));
typedef float f32x4 __attribute__((ext_vector_type(4)));

typedef __attribute__((address_space(1))) void as1_void;
typedef __attribute__((address_space(3))) void as3_void;

__device__ __forceinline__ void gld16(const void* g, void* l) {
  __builtin_amdgcn_global_load_lds((as1_void*)g, (as3_void*)l, 16, 0, 0);
}

__device__ __forceinline__ unsigned short f2b(float f) {  // f32 -> bf16 (RNE)
  unsigned int u = __builtin_bit_cast(unsigned int, f);
  u += 0x7FFFu + ((u >> 16) & 1u);
  return (unsigned short)(u >> 16);
}
__device__ __forceinline__ float b2f(unsigned short b) {
  unsigned int u = ((unsigned int)b) << 16;
  return __builtin_bit_cast(float, u);
}

#define EXP_SHIFT 46.0f

// ---------------- transpose: wq,wk f32 [768][768] -> wqT,wkT f16 (dst[d][o]=src[o][d]) ----
__global__ __launch_bounds__(256) void tr_kernel(const float* __restrict__ wq,
                                                 const float* __restrict__ wk,
                                                 f16* __restrict__ wqT,
                                                 f16* __restrict__ wkT) {
  const int t = threadIdx.x;
  const int id = blockIdx.x;  // 0..71
  const int zz = id / 36, r = id % 36;
  const int br = (r / 6) * 128;  // source row base (o)
  const int bc = (r % 6) * 128;  // source col base (d)
  const float* src = zz ? wk : wq;
  f16* dst = zz ? wkT : wqT;
  __shared__ f16 tile[128][132];
#pragma unroll
  for (int c = 0; c < 16; c++) {
    const int row = c * 8 + (t >> 5);
    const int col = (t & 31) * 4;
    float4 v = *(const float4*)(src + (size_t)(br + row) * DIM + bc + col);
    tile[col + 0][row] = (f16)v.x;
    tile[col + 1][row] = (f16)v.y;
    tile[col + 2][row] = (f16)v.z;
    tile[col + 3][row] = (f16)v.w;
  }
  __syncthreads();
#pragma unroll
  for (int c = 0; c < 16; c++) {
    const int drow = c * 8 + (t >> 5);
    const int dcol = (t & 31) * 4;
    f16x4 o;
    o[0] = tile[drow][dcol + 0];
    o[1] = tile[drow][dcol + 1];
    o[2] = tile[drow][dcol + 2];
    o[3] = tile[drow][dcol + 3];
    *(f16x4*)(dst + (size_t)(bc + drow) * DIM + br + dcol) = o;
  }
}

// ---------------- u[d]=sum_o Wq[o,d]bk[o]; w[e]=sum_o Wk[o,e]bq[o]; c=bq.bk ----------------
__global__ __launch_bounds__(256) void uwc_kernel(const f16* __restrict__ wqT,
                                                  const f16* __restrict__ wkT,
                                                  const float* __restrict__ bq,
                                                  const float* __restrict__ bk,
                                                  float* __restrict__ u,
                                                  float* __restrict__ w,
                                                  float* __restrict__ cbuf) {
  const int b = blockIdx.x;
  const int t = threadIdx.x;
  const int lane = t & 63, wvi = t >> 6;
  if (b == 24) {
    if (wvi == 0) {
      float ss = 0.f;
      for (int i = lane; i < DIM; i += 64) ss += bq[i] * bk[i];
#pragma unroll
      for (int o = 32; o; o >>= 1) ss += __shfl_down(ss, o);
      if (lane == 0) *cbuf = ss;
    }
    return;
  }
  const f16* Ms = (b < 12) ? wqT : wkT;
  const float* vec = (b < 12) ? bk : bq;
  float* dst = (b < 12) ? u : w;
  const int rbase = (b % 12) * 64 + wvi * 16;
  float va[8], vb[4];
#pragma unroll
  for (int e = 0; e < 8; e++) va[e] = vec[lane * 8 + e];
#pragma unroll
  for (int e = 0; e < 4; e++) vb[e] = vec[512 + lane * 4 + e];
  for (int rr = 0; rr < 16; rr++) {
    const int d = rbase + rr;
    const f16* row = Ms + (size_t)d * DIM;
    f16x8 a = *(const f16x8*)(row + lane * 8);
    f16x4 b4 = *(const f16x4*)(row + 512 + lane * 4);
    float ss = 0.f;
#pragma unroll
    for (int e = 0; e < 8; e++) ss += (float)a[e] * va[e];
#pragma unroll
    for (int e = 0; e < 4; e++) ss += (float)b4[e] * vb[e];
#pragma unroll
    for (int o = 32; o; o >>= 1) ss += __shfl_down(ss, o);
    if (lane == 0) dst[d] = ss;
  }
}

// ---------------- wv f32 -> f16 ----------------
__global__ __launch_bounds__(256) void cvt_wv_kernel(const float* __restrict__ src,
                                                     f16* __restrict__ dst) {
  const int i = (blockIdx.x * 256 + threadIdx.x) * 4;
  float4 v = *(const float4*)(src + i);
  f16x4 o;
  o[0] = (f16)v.x; o[1] = (f16)v.y; o[2] = (f16)v.z; o[3] = (f16)v.w;
  *(f16x4*)(dst + i) = o;
}

// ---------------- LayerNorm + rank-1 terms: r=u.xn+c, s=w.xn ----------------
__global__ __launch_bounds__(256) void ln_kernel(const float* __restrict__ x,
                                                 const float* __restrict__ gamma,
                                                 const float* __restrict__ beta,
                                                 const float* __restrict__ u,
                                                 const float* __restrict__ w,
                                                 const float* __restrict__ cbuf,
                                                 f16* __restrict__ xn,
                                                 float* __restrict__ rvec,
                                                 float* __restrict__ svec) {
  const int row = blockIdx.x;
  const int t = threadIdx.x;
  const float* xr = x + (size_t)row * DIM;
  float v0 = xr[t], v1 = xr[t + 256], v2 = xr[t + 512];
  float s = v0 + v1 + v2;
  float s2 = v0 * v0 + v1 * v1 + v2 * v2;
#pragma unroll
  for (int o = 32; o > 0; o >>= 1) {
    s += __shfl_down(s, o);
    s2 += __shfl_down(s2, o);
  }
  __shared__ float red[8];
  const int wv = t >> 6;
  if ((t & 63) == 0) { red[wv] = s; red[4 + wv] = s2; }
  __syncthreads();
  s = red[0] + red[1] + red[2] + red[3];
  s2 = red[4] + red[5] + red[6] + red[7];
  const float mu = s * (1.0f / DIM);
  const float var = s2 * (1.0f / DIM) - mu * mu;
  const float inv = rsqrtf(var + 1e-5f);
  const float y0 = (v0 - mu) * inv * gamma[t] + beta[t];
  const float y1 = (v1 - mu) * inv * gamma[t + 256] + beta[t + 256];
  const float y2 = (v2 - mu) * inv * gamma[t + 512] + beta[t + 512];
  f16* xo = xn + (size_t)row * DIM;
  xo[t] = (f16)y0; xo[t + 256] = (f16)y1; xo[t + 512] = (f16)y2;
  float rp = u[t] * y0 + u[t + 256] * y1 + u[t + 512] * y2;
  float sp = w[t] * y0 + w[t + 256] * y1 + w[t + 512] * y2;
#pragma unroll
  for (int o = 32; o > 0; o >>= 1) {
    rp += __shfl_down(rp, o);
    sp += __shfl_down(sp, o);
  }
  __syncthreads();
  if ((t & 63) == 0) { red[wv] = rp; red[4 + wv] = sp; }
  __syncthreads();
  if (t == 0) {
    rvec[row] = red[0] + red[1] + red[2] + red[3] + cbuf[0];
    svec[row] = red[4] + red[5] + red[6] + red[7];
  }
}

// ================= 128x128 BT-GEMM, multi-block/CU (m97 structure) =================
// C[m,n] = sum_k A[m,k]*B[n,k]. 256 threads = 4 waves (2x2), per-wave 64x64.
// T2 both-sides swizzle, invariant: LDS[row][slot] = data[row][slot ^ (row&7)].
// MODE 0: A=xn, B=wc (z=0 -> M -> Kt f16 no bias; z=1 -> Wv -> Vt bf16 +bv). grid 1536.
// MODE 1: E = bf16(exp(xn.Kt^T + r_i + s_j - 46)); row sums -> lsum atomics. grid nb*256.
// MODE 2: O = (E Vt) * (1/lsum[row]), bf16 MFMA, f32 out. bias0=lsum. grid nb*96.
// MODE 3: M = BT(wqT, wkT) f16 out. grid 36, no XCD swizzle.
template <int MODE>
__global__ __launch_bounds__(256, 4) void gemm_s(const f16* __restrict__ Abase,
                                                 const f16* __restrict__ Bbase,
                                                 void* __restrict__ Out0,
                                                 void* __restrict__ Out1,
                                                 void* __restrict__ Out2,
                                                 const float* __restrict__ bias0,
                                                 const float* __restrict__ bias1,
                                                 const float* __restrict__ bias2,
                                                 int Kdim) {
  const int tid = threadIdx.x;
  const int lane = tid & 63;
  const int w = tid >> 6;
  const int wr = w >> 1, wc = w & 1;

  const int nwg = gridDim.x;
  const int fb = blockIdx.x;
  const int v = (MODE == 3) ? fb : ((fb & 7) * (nwg >> 3) + (fb >> 3));

  int bm, z, bncol;
  const f16 *Ap, *Bp;
  size_t lda, ldb;
  if constexpr (MODE == 0) {
    const int m = v / 12, q12 = v % 12;
    z = q12 / 6; bncol = (q12 % 6) * 128; bm = m * 128;
    Ap = Abase + (size_t)bm * DIM;                              lda = DIM;
    Bp = Bbase + (size_t)z * DIM * DIM + (size_t)bncol * DIM;   ldb = DIM;
  } else if constexpr (MODE == 1) {
    z = v >> 8; const int r = v & 255;
    bm = (r >> 4) * 128; bncol = (r & 15) * 128;
    Ap = Abase + (size_t)z * SEQ * DIM + (size_t)bm * DIM;      lda = DIM;
    Bp = Bbase + (size_t)z * SEQ * DIM + (size_t)bncol * DIM;   ldb = DIM;
  } else if constexpr (MODE == 2) {
    z = v / 96; const int r = v % 96;
    bm = (r / 6) * 128; bncol = (r % 6) * 128;
    Ap = Abase + (size_t)z * SEQ * SEQ + (size_t)bm * SEQ;      lda = SEQ;
    Bp = Bbase + (size_t)z * DIM * SEQ + (size_t)bncol * SEQ;   ldb = SEQ;
  } else {
    const int m = v / 6, n = v % 6;
    z = 0; bm = m * 128; bncol = n * 128;
    Ap = Abase + (size_t)bm * DIM;                              lda = DIM;
    Bp = Bbase + (size_t)bncol * DIM;                           ldb = DIM;
  }
  const int K = Kdim;

  __shared__ __align__(16) f16 As[128 * 64];
  __shared__ __align__(16) f16 Bs[128 * 64];

  const int srow = w * 8 + (lane >> 3);
  const int sslot = (lane & 7) ^ (lane >> 3);
  const f16* ga = Ap + (size_t)srow * lda + sslot * 8;
  const f16* gb = Bp + (size_t)srow * ldb + sslot * 8;

  f32x4 acc[4][4];
#pragma unroll
  for (int i = 0; i < 4; i++)
#pragma unroll
    for (int j = 0; j < 4; j++) acc[i][j] = (f32x4){0.f, 0.f, 0.f, 0.f};

  const int g4 = lane >> 4;
  const int rx = lane & 7;

  const int nk = K >> 6;
  for (int kt = 0; kt < nk; ++kt) {
    const size_t k0 = (size_t)kt << 6;
    __syncthreads();
#pragma unroll
    for (int i = 0; i < 4; i++) {
      gld16(ga + (size_t)(i * 32) * lda + k0, &As[(i * 32 + w * 8) * 64]);
      gld16(gb + (size_t)(i * 32) * ldb + k0, &Bs[(i * 32 + w * 8) * 64]);
    }
    __builtin_amdgcn_s_waitcnt(0);
    __syncthreads();
#pragma unroll
    for (int ks = 0; ks < 2; ++ks) {
      const int sl = ((ks * 4 + g4) ^ rx) * 8;
      f16x8 af[4], bf[4];
#pragma unroll
      for (int i = 0; i < 4; i++)
        af[i] = *(const f16x8*)(&As[(wr * 64 + i * 16 + (lane & 15)) * 64 + sl]);
#pragma unroll
      for (int j = 0; j < 4; j++)
        bf[j] = *(const f16x8*)(&Bs[(wc * 64 + j * 16 + (lane & 15)) * 64 + sl]);
#pragma unroll
      for (int i = 0; i < 4; i++)
#pragma unroll
        for (int j = 0; j < 4; j++) {
          if constexpr (MODE == 2)
            acc[i][j] = __builtin_amdgcn_mfma_f32_16x16x32_bf16(
                __builtin_bit_cast(s16x8, af[i]), __builtin_bit_cast(s16x8, bf[j]),
                acc[i][j], 0, 0, 0);
          else
            acc[i][j] = __builtin_amdgcn_mfma_f32_16x16x32_f16(af[i], bf[j], acc[i][j], 0, 0, 0);
        }
    }
  }

  const int lrow = (lane >> 4) * 4;
  const int lcol = lane & 15;

  if constexpr (MODE == 0) {
    if (z == 0) {
      f16* Oz = (f16*)Out0;  // Kt f16, no bias
#pragma unroll
      for (int j = 0; j < 4; j++) {
        const int gc = bncol + wc * 64 + j * 16 + lcol;
#pragma unroll
        for (int i = 0; i < 4; i++) {
          const int grow = bm + wr * 64 + i * 16 + lrow;
          f16* o = Oz + (size_t)grow * DIM + gc;
          o[0 * DIM] = (f16)acc[i][j][0];
          o[1 * DIM] = (f16)acc[i][j][1];
          o[2 * DIM] = (f16)acc[i][j][2];
          o[3 * DIM] = (f16)acc[i][j][3];
        }
      }
    } else {
      unsigned short* Vt = (unsigned short*)Out2;  // bf16 [NB][DIM][SEQ]
#pragma unroll
      for (int j = 0; j < 4; j++) {
        const int gc = bncol + wc * 64 + j * 16 + lcol;
        const float bb = bias2[gc];
#pragma unroll
        for (int i = 0; i < 4; i++) {
          const int grow = bm + wr * 64 + i * 16 + lrow;
          const int bidx = grow >> 11, nt = grow & (SEQ - 1);
          u16x4 pk;
          pk[0] = f2b(acc[i][j][0] + bb);
          pk[1] = f2b(acc[i][j][1] + bb);
          pk[2] = f2b(acc[i][j][2] + bb);
          pk[3] = f2b(acc[i][j][3] + bb);
          *(u16x4*)(Vt + ((size_t)bidx * DIM + gc) * SEQ + nt) = pk;
        }
      }
    }
  } else if constexpr (MODE == 1) {
    unsigned short* Oz = (unsigned short*)Out0 + (size_t)z * SEQ * SEQ;  // E bf16
    float* lsum = (float*)Out1;
    float r16[4][4];
#pragma unroll
    for (int i = 0; i < 4; i++)
#pragma unroll
      for (int r = 0; r < 4; r++)
        r16[i][r] = bias1[(size_t)z * SEQ + bm + wr * 64 + i * 16 + lrow + r];
    float rs[4][4];
#pragma unroll
    for (int i = 0; i < 4; i++)
#pragma unroll
      for (int r = 0; r < 4; r++) rs[i][r] = 0.f;
#pragma unroll
    for (int j = 0; j < 4; j++) {
      const int gc = bncol + wc * 64 + j * 16 + lcol;
      const float sc = bias2[(size_t)z * SEQ + gc];
#pragma unroll
      for (int i = 0; i < 4; i++) {
        const int grow = bm + wr * 64 + i * 16 + lrow;
        unsigned short* o = Oz + (size_t)grow * SEQ + gc;
#pragma unroll
        for (int r = 0; r < 4; r++) {
          const unsigned short eb = f2b(__expf(acc[i][j][r] + r16[i][r] + sc - EXP_SHIFT));
          o[(size_t)r * SEQ] = eb;
          rs[i][r] += b2f(eb);
        }
      }
    }
#pragma unroll
    for (int i = 0; i < 4; i++)
#pragma unroll
      for (int r = 0; r < 4; r++) {
        float s = rs[i][r];
        s += __shfl_xor(s, 1);
        s += __shfl_xor(s, 2);
        s += __shfl_xor(s, 4);
        s += __shfl_xor(s, 8);
        if ((lane & 15) == 0)
          atomicAdd(lsum + (size_t)z * SEQ + bm + wr * 64 + i * 16 + lrow + r, s);
      }
  } else if constexpr (MODE == 2) {
    const float* lsum = bias0;
    float invl[4][4];
#pragma unroll
    for (int i = 0; i < 4; i++)
#pragma unroll
      for (int r = 0; r < 4; r++)
        invl[i][r] = 1.0f / lsum[(size_t)z * SEQ + bm + wr * 64 + i * 16 + lrow + r];
    float* Oz = (float*)Out0 + (size_t)z * SEQ * DIM;
#pragma unroll
    for (int j = 0; j < 4; j++) {
      const int gc = bncol + wc * 64 + j * 16 + lcol;
#pragma unroll
      for (int i = 0; i < 4; i++) {
        const int grow = bm + wr * 64 + i * 16 + lrow;
        float* o = Oz + (size_t)grow * DIM + gc;
        o[0 * DIM] = acc[i][j][0] * invl[i][0];
        o[1 * DIM] = acc[i][j][1] * invl[i][1];
        o[2 * DIM] = acc[i][j][2] * invl[i][2];
        o[3 * DIM] = acc[i][j][3] * invl[i][3];
      }
    }
  } else {  // MODE 3: M f16
    f16* Oz = (f16*)Out0;
#pragma unroll
    for (int j = 0; j < 4; j++) {
      const int gc = bncol + wc * 64 + j * 16 + lcol;
#pragma unroll
      for (int i = 0; i < 4; i++) {
        const int grow = bm + wr * 64 + i * 16 + lrow;
        f16* o = Oz + (size_t)grow * DIM + gc;
        o[0 * DIM] = (f16)acc[i][j][0];
        o[1 * DIM] = (f16)acc[i][j][1];
        o[2 * DIM] = (f16)acc[i][j][2];
        o[3 * DIM] = (f16)acc[i][j][3];
      }
    }
  }
}

extern "C" void kernel_launch(void* const* d_in, const int* in_sizes, int n_in,
                              void* d_out, int out_size, void* d_ws, size_t ws_size,
                              hipStream_t stream) {
  (void)in_sizes; (void)n_in; (void)out_size;
  const float* x  = (const float*)d_in[0];
  const float* lg = (const float*)d_in[1];
  const float* lb = (const float*)d_in[2];
  const float* wq = (const float*)d_in[3];
  const float* bq = (const float*)d_in[4];
  const float* wk = (const float*)d_in[5];
  const float* bk = (const float*)d_in[6];
  const float* wv = (const float*)d_in[7];
  const float* bv = (const float*)d_in[8];
  float* out = (float*)d_out;

  const size_t MT = (size_t)NB * SEQ;  // 16384 tokens
  f16* xn  = (f16*)d_ws;                         // [16384][768] f16
  f16* wcb = xn + MT * DIM;                      // [2][768][768]: slot0 = M, slot1 = Wv
  f16* wqT = wcb + (size_t)2 * DIM * DIM;        // [768][768] f16 transposed
  f16* wkT = wqT + (size_t)DIM * DIM;
  f16* Kt  = wkT + (size_t)DIM * DIM;            // [16384][768] f16
  unsigned short* Vt = (unsigned short*)(Kt + MT * DIM);  // [8][768][2048] bf16
  float* uv  = (float*)(Vt + MT * DIM);          // [768]
  float* wv2 = uv + DIM;                         // [768]
  float* cb  = wv2 + DIM;                        // [4]
  float* rv  = cb + 4;                           // [16384]
  float* sv  = rv + MT;                          // [16384]
  char* dyn = (char*)(sv + MT);
  const size_t used = (size_t)(dyn - (char*)d_ws);
  const size_t per_batch = (size_t)SEQ * SEQ * 2 + (size_t)SEQ * 4;  // E bf16 + lsum
  size_t rem = (ws_size > used) ? (ws_size - used) : 0;
  int nbc = (int)(rem / per_batch);
  if (nbc < 1) nbc = 1;
  if (nbc > NB) nbc = NB;
  unsigned short* E = (unsigned short*)dyn;                    // [nbc][SEQ][SEQ] bf16
  float* lsum = (float*)(dyn + (size_t)nbc * SEQ * SEQ * 2);   // [nbc*SEQ]

  tr_kernel<<<dim3(72), 256, 0, stream>>>(wq, wk, wqT, wkT);
  uwc_kernel<<<dim3(25), 256, 0, stream>>>(wqT, wkT, bq, bk, uv, wv2, cb);
  cvt_wv_kernel<<<dim3(576), 256, 0, stream>>>(wv, wcb + (size_t)DIM * DIM);
  gemm_s<3><<<dim3(36), 256, 0, stream>>>(wqT, wkT, wcb, nullptr, nullptr,
                                          nullptr, nullptr, nullptr, DIM);
  ln_kernel<<<dim3((unsigned)MT), 256, 0, stream>>>(x, lg, lb, uv, wv2, cb, xn, rv, sv);
  gemm_s<0><<<dim3(128 * 12), 256, 0, stream>>>(xn, wcb, Kt, nullptr, Vt,
                                                nullptr, nullptr, bv, DIM);

  for (int b0 = 0; b0 < NB; b0 += nbc) {
    const int nb = (NB - b0 < nbc) ? (NB - b0) : nbc;
    hipMemsetAsync(lsum, 0, (size_t)nb * SEQ * 4, stream);
    gemm_s<1><<<dim3(nb * 256), 256, 0, stream>>>(
        xn + (size_t)b0 * SEQ * DIM, Kt + (size_t)b0 * SEQ * DIM,
        E, lsum, nullptr, nullptr, rv + (size_t)b0 * SEQ, sv + (size_t)b0 * SEQ, DIM);
    gemm_s<2><<<dim3(nb * 96), 256, 0, stream>>>(
        (const f16*)E, (const f16*)(Vt + (size_t)b0 * DIM * SEQ),
        out + (size_t)b0 * SEQ * DIM, nullptr, nullptr, lsum, nullptr, nullptr, SEQ);
  }
}

// Round 10
// 260.570 us; speedup vs baseline: 1.0603x; 1.0603x over previous
//
#include <hip/hip_runtime.h>

#define NB 8
#define SEQ 2048
#define DIM 768

typedef _Float16 f16;
typedef _Float16 f16x8 __attribute__((ext_vector_type(8)));
typedef _Float16 f16x4 __attribute__((ext_vector_type(4)));
typedef short s16x8 __attribute__((ext_vector_type(8)));
typedef unsigned short u16x4 __attribute__((ext_vector_type(4)));
typedef float f32x4 __attribute__((ext_vector_type(4)));

typedef __attribute__((address_space(1))) void as1_void;
typedef __attribute__((address_space(3))) void as3_void;

__device__ __forceinline__ void gld16(const void* g, void* l) {
  __builtin_amdgcn_global_load_lds((as1_void*)g, (as3_void*)l, 16, 0, 0);
}

__device__ __forceinline__ unsigned short f2b(float f) {  // f32 -> bf16 (RNE)
  unsigned int u = __builtin_bit_cast(unsigned int, f);
  u += 0x7FFFu + ((u >> 16) & 1u);
  return (unsigned short)(u >> 16);
}
__device__ __forceinline__ float b2f(unsigned short b) {
  unsigned int u = ((unsigned int)b) << 16;
  return __builtin_bit_cast(float, u);
}

#define EXP_SHIFT 46.0f

// ---------------- LayerNorm: fp32 x -> fp16 xn ----------------
__global__ __launch_bounds__(256) void ln_kernel(const float* __restrict__ x,
                                                 const float* __restrict__ gamma,
                                                 const float* __restrict__ beta,
                                                 f16* __restrict__ xn) {
  const int row = blockIdx.x;
  const int t = threadIdx.x;
  const float* xr = x + (size_t)row * DIM;
  float v0 = xr[t], v1 = xr[t + 256], v2 = xr[t + 512];
  float s = v0 + v1 + v2;
  float s2 = v0 * v0 + v1 * v1 + v2 * v2;
#pragma unroll
  for (int o = 32; o > 0; o >>= 1) {
    s += __shfl_down(s, o);
    s2 += __shfl_down(s2, o);
  }
  __shared__ float red[8];
  const int w = t >> 6;
  if ((t & 63) == 0) { red[w] = s; red[4 + w] = s2; }
  __syncthreads();
  s = red[0] + red[1] + red[2] + red[3];
  s2 = red[4] + red[5] + red[6] + red[7];
  const float mu = s * (1.0f / DIM);
  const float var = s2 * (1.0f / DIM) - mu * mu;
  const float inv = rsqrtf(var + 1e-5f);
  f16* xo = xn + (size_t)row * DIM;
  xo[t]       = (f16)((v0 - mu) * inv * gamma[t]       + beta[t]);
  xo[t + 256] = (f16)((v1 - mu) * inv * gamma[t + 256] + beta[t + 256]);
  xo[t + 512] = (f16)((v2 - mu) * inv * gamma[t + 512] + beta[t + 512]);
}

// ---------------- weight convert fp32 -> fp16, wq|wk|wv concatenated ----------------
__global__ __launch_bounds__(256) void cvt_w_kernel(const float* __restrict__ wq,
                                                    const float* __restrict__ wk,
                                                    const float* __restrict__ wv,
                                                    f16* __restrict__ wcat) {
  const int i = (blockIdx.x * 256 + threadIdx.x) * 4;
  const int per = DIM * DIM;
  const float* src;
  int rem;
  if (i < per) { src = wq; rem = i; }
  else if (i < 2 * per) { src = wk; rem = i - per; }
  else { src = wv; rem = i - 2 * per; }
  float4 v = *(const float4*)(src + rem);
  f16x4 o;
  o[0] = (f16)v.x; o[1] = (f16)v.y; o[2] = (f16)v.z; o[3] = (f16)v.w;
  *(f16x4*)(wcat + i) = o;
}

// ================= 128x128 BT-GEMM, multi-block/CU (m97 structure) =================
// C[m,n] = sum_k A[m,k]*B[n,k]. 256 threads = 4 waves (2x2), per-wave 64x64.
// 32KB LDS + launch_bounds(256,5) -> 5 blocks/CU (LDS-exact); TLP hides staging.
// T2 both-sides swizzle, invariant: LDS[row][slot] = data[row][slot ^ (row&7)].
// MODE 0: QKV. f16 in -> Q f16, K f16 (+bias); z==2 -> Vt bf16 [NB][DIM][SEQ] (+bias).
// MODE 1: E = bf16(exp(Q K^T - 46)) per batch; row sums into lsum (Out1) via atomics.
// MODE 2: O = (E Vt) * (1/lsum[row]), bf16 MFMA, f32 out. bias0 = lsum.
template <int MODE>
__global__ __launch_bounds__(256, 5) void gemm_s(const f16* __restrict__ Abase,
                                                 const f16* __restrict__ Bbase,
                                                 void* __restrict__ Out0,
                                                 void* __restrict__ Out1,
                                                 void* __restrict__ Out2,
                                                 const float* __restrict__ bias0,
                                                 const float* __restrict__ bias1,
                                                 const float* __restrict__ bias2,
                                                 int Kdim) {
  const int tid = threadIdx.x;
  const int lane = tid & 63;
  const int w = tid >> 6;
  const int wr = w >> 1, wc = w & 1;

  // XCD-aware bijective swizzle (grid % 8 == 0 by construction)
  const int nwg = gridDim.x;
  const int fb = blockIdx.x;
  const int v = (fb & 7) * (nwg >> 3) + (fb >> 3);

  int bm, z, bncol;
  const f16 *Ap, *Bp;
  size_t lda, ldb;
  if constexpr (MODE == 0) {
    const int m = v / 18, u = v % 18;
    z = u / 6; bncol = (u % 6) * 128; bm = m * 128;
    Ap = Abase + (size_t)bm * DIM;                              lda = DIM;
    Bp = Bbase + (size_t)z * DIM * DIM + (size_t)bncol * DIM;   ldb = DIM;
  } else if constexpr (MODE == 1) {
    z = v >> 8; const int r = v & 255;
    bm = (r >> 4) * 128; bncol = (r & 15) * 128;
    Ap = Abase + (size_t)z * SEQ * DIM + (size_t)bm * DIM;      lda = DIM;
    Bp = Bbase + (size_t)z * SEQ * DIM + (size_t)bncol * DIM;   ldb = DIM;
  } else {
    z = v / 96; const int r = v % 96;
    bm = (r / 6) * 128; bncol = (r % 6) * 128;
    Ap = Abase + (size_t)z * SEQ * SEQ + (size_t)bm * SEQ;      lda = SEQ;
    Bp = Bbase + (size_t)z * DIM * SEQ + (size_t)bncol * SEQ;   ldb = SEQ;
  }
  const int K = Kdim;

  __shared__ __align__(16) f16 As[128 * 64];
  __shared__ __align__(16) f16 Bs[128 * 64];

  const int srow = w * 8 + (lane >> 3);              // staged row (per 32-row chunk)
  const int sslot = (lane & 7) ^ (lane >> 3);        // swizzled 16B slot (row&7 == lane>>3)
  const f16* ga = Ap + (size_t)srow * lda + sslot * 8;  // pre-swizzled source (gld_lds)
  const f16* gb = Bp + (size_t)srow * ldb + sslot * 8;

  f32x4 acc[4][4];
#pragma unroll
  for (int i = 0; i < 4; i++)
#pragma unroll
    for (int j = 0; j < 4; j++) acc[i][j] = (f32x4){0.f, 0.f, 0.f, 0.f};

  const int g4 = lane >> 4;   // k-slot group 0..3
  const int rx = lane & 7;    // row&7 for fragment rows

  const int nk = K >> 6;
  for (int kt = 0; kt < nk; ++kt) {
    const size_t k0 = (size_t)kt << 6;
    __syncthreads();  // previous iteration's readers done
#pragma unroll
    for (int i = 0; i < 4; i++) {
      gld16(ga + (size_t)(i * 32) * lda + k0, &As[(i * 32 + w * 8) * 64]);
      gld16(gb + (size_t)(i * 32) * ldb + k0, &Bs[(i * 32 + w * 8) * 64]);
    }
    __builtin_amdgcn_s_waitcnt(0);
    __syncthreads();
#pragma unroll
    for (int ks = 0; ks < 2; ++ks) {
      const int sl = ((ks * 4 + g4) ^ rx) * 8;
      f16x8 af[4], bf[4];
#pragma unroll
      for (int i = 0; i < 4; i++)
        af[i] = *(const f16x8*)(&As[(wr * 64 + i * 16 + (lane & 15)) * 64 + sl]);
#pragma unroll
      for (int j = 0; j < 4; j++)
        bf[j] = *(const f16x8*)(&Bs[(wc * 64 + j * 16 + (lane & 15)) * 64 + sl]);
#pragma unroll
      for (int i = 0; i < 4; i++)
#pragma unroll
        for (int j = 0; j < 4; j++) {
          if constexpr (MODE == 2)
            acc[i][j] = __builtin_amdgcn_mfma_f32_16x16x32_bf16(
                __builtin_bit_cast(s16x8, af[i]), __builtin_bit_cast(s16x8, bf[j]),
                acc[i][j], 0, 0, 0);
          else
            acc[i][j] = __builtin_amdgcn_mfma_f32_16x16x32_f16(af[i], bf[j], acc[i][j], 0, 0, 0);
        }
    }
  }

  // epilogue: C fragment layout col=lane&15, row=(lane>>4)*4+r
  const int lrow = (lane >> 4) * 4;
  const int lcol = lane & 15;

  if constexpr (MODE == 0) {
    const float* bias = (z == 0) ? bias0 : (z == 1) ? bias1 : bias2;
    if (z < 2) {
      f16* Oz = (f16*)((z == 0) ? Out0 : Out1);
#pragma unroll
      for (int j = 0; j < 4; j++) {
        const int gc = bncol + wc * 64 + j * 16 + lcol;
        const float bb = bias[gc];
#pragma unroll
        for (int i = 0; i < 4; i++) {
          const int grow = bm + wr * 64 + i * 16 + lrow;
          f16* o = Oz + (size_t)grow * DIM + gc;
          o[0 * DIM] = (f16)(acc[i][j][0] + bb);
          o[1 * DIM] = (f16)(acc[i][j][1] + bb);
          o[2 * DIM] = (f16)(acc[i][j][2] + bb);
          o[3 * DIM] = (f16)(acc[i][j][3] + bb);
        }
      }
    } else {
      unsigned short* Vt = (unsigned short*)Out2;  // bf16 [NB][DIM][SEQ]
#pragma unroll
      for (int j = 0; j < 4; j++) {
        const int gc = bncol + wc * 64 + j * 16 + lcol;  // output-dim index
        const float bb = bias[gc];
#pragma unroll
        for (int i = 0; i < 4; i++) {
          const int grow = bm + wr * 64 + i * 16 + lrow;  // global token index
          const int bidx = grow >> 11, nt = grow & (SEQ - 1);
          u16x4 pk;
          pk[0] = f2b(acc[i][j][0] + bb);
          pk[1] = f2b(acc[i][j][1] + bb);
          pk[2] = f2b(acc[i][j][2] + bb);
          pk[3] = f2b(acc[i][j][3] + bb);
          *(u16x4*)(Vt + ((size_t)bidx * DIM + gc) * SEQ + nt) = pk;
        }
      }
    }
  } else if constexpr (MODE == 1) {
    unsigned short* Oz = (unsigned short*)Out0 + (size_t)z * SEQ * SEQ;  // E bf16
    float* lsum = (float*)Out1;
    float rs[4][4];
#pragma unroll
    for (int i = 0; i < 4; i++)
#pragma unroll
      for (int r = 0; r < 4; r++) rs[i][r] = 0.f;
#pragma unroll
    for (int j = 0; j < 4; j++) {
      const int gc = bncol + wc * 64 + j * 16 + lcol;
#pragma unroll
      for (int i = 0; i < 4; i++) {
        const int grow = bm + wr * 64 + i * 16 + lrow;
        unsigned short* o = Oz + (size_t)grow * SEQ + gc;
#pragma unroll
        for (int r = 0; r < 4; r++) {
          const unsigned short eb = f2b(__expf(acc[i][j][r] - EXP_SHIFT));
          o[(size_t)r * SEQ] = eb;
          rs[i][r] += b2f(eb);
        }
      }
    }
    // reduce each row partial across the 16 lanes of this g-group, one atomic per row
#pragma unroll
    for (int i = 0; i < 4; i++)
#pragma unroll
      for (int r = 0; r < 4; r++) {
        float s = rs[i][r];
        s += __shfl_xor(s, 1);
        s += __shfl_xor(s, 2);
        s += __shfl_xor(s, 4);
        s += __shfl_xor(s, 8);
        if ((lane & 15) == 0)
          atomicAdd(lsum + (size_t)z * SEQ + bm + wr * 64 + i * 16 + lrow + r, s);
      }
  } else {
    const float* lsum = bias0;
    float invl[4][4];
#pragma unroll
    for (int i = 0; i < 4; i++)
#pragma unroll
      for (int r = 0; r < 4; r++)
        invl[i][r] = 1.0f / lsum[(size_t)z * SEQ + bm + wr * 64 + i * 16 + lrow + r];
    float* Oz = (float*)Out0 + (size_t)z * SEQ * DIM;
#pragma unroll
    for (int j = 0; j < 4; j++) {
      const int gc = bncol + wc * 64 + j * 16 + lcol;
#pragma unroll
      for (int i = 0; i < 4; i++) {
        const int grow = bm + wr * 64 + i * 16 + lrow;
        float* o = Oz + (size_t)grow * DIM + gc;
        o[0 * DIM] = acc[i][j][0] * invl[i][0];
        o[1 * DIM] = acc[i][j][1] * invl[i][1];
        o[2 * DIM] = acc[i][j][2] * invl[i][2];
        o[3 * DIM] = acc[i][j][3] * invl[i][3];
      }
    }
  }
}

extern "C" void kernel_launch(void* const* d_in, const int* in_sizes, int n_in,
                              void* d_out, int out_size, void* d_ws, size_t ws_size,
                              hipStream_t stream) {
  (void)in_sizes; (void)n_in; (void)out_size;
  const float* x  = (const float*)d_in[0];
  const float* lg = (const float*)d_in[1];
  const float* lb = (const float*)d_in[2];
  const float* wq = (const float*)d_in[3];
  const float* bq = (const float*)d_in[4];
  const float* wk = (const float*)d_in[5];
  const float* bk = (const float*)d_in[6];
  const float* wv = (const float*)d_in[7];
  const float* bv = (const float*)d_in[8];
  float* out = (float*)d_out;

  const size_t MT = (size_t)NB * SEQ;  // 16384 tokens
  f16* xn  = (f16*)d_ws;               // [16384][768] f16
  f16* wc  = xn + MT * DIM;            // [3][768][768] f16
  f16* Q   = wc + (size_t)3 * DIM * DIM;
  f16* Km  = Q + MT * DIM;
  unsigned short* Vt = (unsigned short*)(Km + MT * DIM);  // [8][768][2048] bf16
  float* lsum = (float*)(Vt + MT * DIM);                  // [NB*SEQ] f32, fixed
  char* dyn = (char*)(lsum + MT);
  const size_t used = (size_t)(dyn - (char*)d_ws);
  const size_t per_batch = (size_t)SEQ * SEQ * 2;  // E bf16
  size_t rem = (ws_size > used) ? (ws_size - used) : 0;
  int nbc = (int)(rem / per_batch);
  if (nbc < 1) nbc = 1;
  if (nbc > NB) nbc = NB;
  unsigned short* E = (unsigned short*)dyn;  // [nbc][SEQ][SEQ] bf16

  cvt_w_kernel<<<dim3(3 * DIM * DIM / 1024), 256, 0, stream>>>(wq, wk, wv, wc);
  ln_kernel<<<dim3((unsigned)MT), 256, 0, stream>>>(x, lg, lb, xn);
  hipMemsetAsync(lsum, 0, MT * 4, stream);
  gemm_s<0><<<dim3(128 * 18), 256, 0, stream>>>(xn, wc, Q, Km, Vt, bq, bk, bv, DIM);

  for (int b0 = 0; b0 < NB; b0 += nbc) {
    const int nb = (NB - b0 < nbc) ? (NB - b0) : nbc;
    gemm_s<1><<<dim3(nb * 256), 256, 0, stream>>>(
        Q + (size_t)b0 * SEQ * DIM, Km + (size_t)b0 * SEQ * DIM,
        E, lsum + (size_t)b0 * SEQ, nullptr, nullptr, nullptr, nullptr, DIM);
    gemm_s<2><<<dim3(nb * 96), 256, 0, stream>>>(
        (const f16*)E, (const f16*)(Vt + (size_t)b0 * DIM * SEQ),
        out + (size_t)b0 * SEQ * DIM, nullptr, nullptr, lsum + (size_t)b0 * SEQ,
        nullptr, nullptr, SEQ);
  }
}

// Round 11
// 229.725 us; speedup vs baseline: 1.2027x; 1.1343x over previous
//
#include <hip/hip_runtime.h>

#define NB 8
#define SEQ 2048
#define DIM 768

typedef _Float16 f16;
typedef _Float16 f16x8 __attribute__((ext_vector_type(8)));
typedef _Float16 f16x4 __attribute__((ext_vector_type(4)));
typedef short s16x8 __attribute__((ext_vector_type(8)));
typedef unsigned short u16x4 __attribute__((ext_vector_type(4)));
typedef float f32x4 __attribute__((ext_vector_type(4)));

typedef __attribute__((address_space(1))) void as1_void;
typedef __attribute__((address_space(3))) void as3_void;

__device__ __forceinline__ void gld16(const void* g, void* l) {
  __builtin_amdgcn_global_load_lds((as1_void*)g, (as3_void*)l, 16, 0, 0);
}

__device__ __forceinline__ unsigned short f2b(float f) {  // f32 -> bf16 (RNE)
  unsigned int u = __builtin_bit_cast(unsigned int, f);
  u += 0x7FFFu + ((u >> 16) & 1u);
  return (unsigned short)(u >> 16);
}
__device__ __forceinline__ float b2f(unsigned short b) {
  unsigned int u = ((unsigned int)b) << 16;
  return __builtin_bit_cast(float, u);
}

#define EXP_SHIFT 46.0f

// ---------------- LayerNorm: fp32 x -> fp16 xn ----------------
__global__ __launch_bounds__(256) void ln_kernel(const float* __restrict__ x,
                                                 const float* __restrict__ gamma,
                                                 const float* __restrict__ beta,
                                                 f16* __restrict__ xn) {
  const int row = blockIdx.x;
  const int t = threadIdx.x;
  const float* xr = x + (size_t)row * DIM;
  float v0 = xr[t], v1 = xr[t + 256], v2 = xr[t + 512];
  float s = v0 + v1 + v2;
  float s2 = v0 * v0 + v1 * v1 + v2 * v2;
#pragma unroll
  for (int o = 32; o > 0; o >>= 1) {
    s += __shfl_down(s, o);
    s2 += __shfl_down(s2, o);
  }
  __shared__ float red[8];
  const int w = t >> 6;
  if ((t & 63) == 0) { red[w] = s; red[4 + w] = s2; }
  __syncthreads();
  s = red[0] + red[1] + red[2] + red[3];
  s2 = red[4] + red[5] + red[6] + red[7];
  const float mu = s * (1.0f / DIM);
  const float var = s2 * (1.0f / DIM) - mu * mu;
  const float inv = rsqrtf(var + 1e-5f);
  f16* xo = xn + (size_t)row * DIM;
  xo[t]       = (f16)((v0 - mu) * inv * gamma[t]       + beta[t]);
  xo[t + 256] = (f16)((v1 - mu) * inv * gamma[t + 256] + beta[t + 256]);
  xo[t + 512] = (f16)((v2 - mu) * inv * gamma[t + 512] + beta[t + 512]);
}

// ---------------- weight convert fp32 -> fp16, wq|wk|wv concatenated ----------------
__global__ __launch_bounds__(256) void cvt_w_kernel(const float* __restrict__ wq,
                                                    const float* __restrict__ wk,
                                                    const float* __restrict__ wv,
                                                    f16* __restrict__ wcat) {
  const int i = (blockIdx.x * 256 + threadIdx.x) * 4;
  const int per = DIM * DIM;
  const float* src;
  int rem;
  if (i < per) { src = wq; rem = i; }
  else if (i < 2 * per) { src = wk; rem = i - per; }
  else { src = wv; rem = i - 2 * per; }
  float4 v = *(const float4*)(src + rem);
  f16x4 o;
  o[0] = (f16)v.x; o[1] = (f16)v.y; o[2] = (f16)v.z; o[3] = (f16)v.w;
  *(f16x4*)(wcat + i) = o;
}

// ================= 128x128 BT-GEMM, multi-block/CU (m97 structure) =================
// C[m,n] = sum_k A[m,k]*B[n,k]. 256 threads = 4 waves (2x2), per-wave 64x64.
// 32KB LDS + launch_bounds(256,4) -> 4 blocks/CU (verified best: 5 thrashes L2).
// T2 both-sides swizzle, invariant: LDS[row][slot] = data[row][slot ^ (row&7)].
// MODE 0: QKV. f16 in -> Q f16, K f16 (+bias); z==2 -> Vt bf16 [NB][DIM][SEQ] (+bias).
// MODE 1: E = bf16(exp(Q K^T - 46)) per batch; row sums into lsum (Out1) via atomics.
// MODE 2: O = (E Vt) * (1/lsum[row]), bf16 MFMA, f32 out. bias0 = lsum.
template <int MODE>
__global__ __launch_bounds__(256, 4) void gemm_s(const f16* __restrict__ Abase,
                                                 const f16* __restrict__ Bbase,
                                                 void* __restrict__ Out0,
                                                 void* __restrict__ Out1,
                                                 void* __restrict__ Out2,
                                                 const float* __restrict__ bias0,
                                                 const float* __restrict__ bias1,
                                                 const float* __restrict__ bias2,
                                                 int Kdim) {
  const int tid = threadIdx.x;
  const int lane = tid & 63;
  const int w = tid >> 6;
  const int wr = w >> 1, wc = w & 1;

  // XCD-aware bijective swizzle (grid % 8 == 0 by construction)
  const int nwg = gridDim.x;
  const int fb = blockIdx.x;
  const int v = (fb & 7) * (nwg >> 3) + (fb >> 3);

  int bm, z, bncol;
  const f16 *Ap, *Bp;
  size_t lda, ldb;
  if constexpr (MODE == 0) {
    const int m = v / 18, u = v % 18;
    z = u / 6; bncol = (u % 6) * 128; bm = m * 128;
    Ap = Abase + (size_t)bm * DIM;                              lda = DIM;
    Bp = Bbase + (size_t)z * DIM * DIM + (size_t)bncol * DIM;   ldb = DIM;
  } else if constexpr (MODE == 1) {
    z = v >> 8; const int r = v & 255;
    bm = (r >> 4) * 128; bncol = (r & 15) * 128;
    Ap = Abase + (size_t)z * SEQ * DIM + (size_t)bm * DIM;      lda = DIM;
    Bp = Bbase + (size_t)z * SEQ * DIM + (size_t)bncol * DIM;   ldb = DIM;
  } else {
    z = v / 96; const int r = v % 96;
    bm = (r / 6) * 128; bncol = (r % 6) * 128;
    Ap = Abase + (size_t)z * SEQ * SEQ + (size_t)bm * SEQ;      lda = SEQ;
    Bp = Bbase + (size_t)z * DIM * SEQ + (size_t)bncol * SEQ;   ldb = SEQ;
  }
  const int K = Kdim;

  __shared__ __align__(16) f16 As[128 * 64];
  __shared__ __align__(16) f16 Bs[128 * 64];

  const int srow = w * 8 + (lane >> 3);              // staged row (per 32-row chunk)
  const int sslot = (lane & 7) ^ (lane >> 3);        // swizzled 16B slot (row&7 == lane>>3)
  const f16* ga = Ap + (size_t)srow * lda + sslot * 8;  // pre-swizzled source (gld_lds)
  const f16* gb = Bp + (size_t)srow * ldb + sslot * 8;

  f32x4 acc[4][4];
#pragma unroll
  for (int i = 0; i < 4; i++)
#pragma unroll
    for (int j = 0; j < 4; j++) acc[i][j] = (f32x4){0.f, 0.f, 0.f, 0.f};

  const int g4 = lane >> 4;   // k-slot group 0..3
  const int rx = lane & 7;    // row&7 for fragment rows

  const int nk = K >> 6;
  for (int kt = 0; kt < nk; ++kt) {
    const size_t k0 = (size_t)kt << 6;
    __syncthreads();  // previous iteration's readers done
#pragma unroll
    for (int i = 0; i < 4; i++) {
      gld16(ga + (size_t)(i * 32) * lda + k0, &As[(i * 32 + w * 8) * 64]);
      gld16(gb + (size_t)(i * 32) * ldb + k0, &Bs[(i * 32 + w * 8) * 64]);
    }
    __builtin_amdgcn_s_waitcnt(0);
    __syncthreads();
#pragma unroll
    for (int ks = 0; ks < 2; ++ks) {
      const int sl = ((ks * 4 + g4) ^ rx) * 8;
      f16x8 af[4], bf[4];
#pragma unroll
      for (int i = 0; i < 4; i++)
        af[i] = *(const f16x8*)(&As[(wr * 64 + i * 16 + (lane & 15)) * 64 + sl]);
#pragma unroll
      for (int j = 0; j < 4; j++)
        bf[j] = *(const f16x8*)(&Bs[(wc * 64 + j * 16 + (lane & 15)) * 64 + sl]);
#pragma unroll
      for (int i = 0; i < 4; i++)
#pragma unroll
        for (int j = 0; j < 4; j++) {
          if constexpr (MODE == 2)
            acc[i][j] = __builtin_amdgcn_mfma_f32_16x16x32_bf16(
                __builtin_bit_cast(s16x8, af[i]), __builtin_bit_cast(s16x8, bf[j]),
                acc[i][j], 0, 0, 0);
          else
            acc[i][j] = __builtin_amdgcn_mfma_f32_16x16x32_f16(af[i], bf[j], acc[i][j], 0, 0, 0);
        }
    }
  }

  // epilogue: C fragment layout col=lane&15, row=(lane>>4)*4+r
  const int lrow = (lane >> 4) * 4;
  const int lcol = lane & 15;

  if constexpr (MODE == 0) {
    const float* bias = (z == 0) ? bias0 : (z == 1) ? bias1 : bias2;
    if (z < 2) {
      f16* Oz = (f16*)((z == 0) ? Out0 : Out1);
#pragma unroll
      for (int j = 0; j < 4; j++) {
        const int gc = bncol + wc * 64 + j * 16 + lcol;
        const float bb = bias[gc];
#pragma unroll
        for (int i = 0; i < 4; i++) {
          const int grow = bm + wr * 64 + i * 16 + lrow;
          f16* o = Oz + (size_t)grow * DIM + gc;
          o[0 * DIM] = (f16)(acc[i][j][0] + bb);
          o[1 * DIM] = (f16)(acc[i][j][1] + bb);
          o[2 * DIM] = (f16)(acc[i][j][2] + bb);
          o[3 * DIM] = (f16)(acc[i][j][3] + bb);
        }
      }
    } else {
      unsigned short* Vt = (unsigned short*)Out2;  // bf16 [NB][DIM][SEQ]
#pragma unroll
      for (int j = 0; j < 4; j++) {
        const int gc = bncol + wc * 64 + j * 16 + lcol;  // output-dim index
        const float bb = bias[gc];
#pragma unroll
        for (int i = 0; i < 4; i++) {
          const int grow = bm + wr * 64 + i * 16 + lrow;  // global token index
          const int bidx = grow >> 11, nt = grow & (SEQ - 1);
          u16x4 pk;
          pk[0] = f2b(acc[i][j][0] + bb);
          pk[1] = f2b(acc[i][j][1] + bb);
          pk[2] = f2b(acc[i][j][2] + bb);
          pk[3] = f2b(acc[i][j][3] + bb);
          *(u16x4*)(Vt + ((size_t)bidx * DIM + gc) * SEQ + nt) = pk;
        }
      }
    }
  } else if constexpr (MODE == 1) {
    unsigned short* Oz = (unsigned short*)Out0 + (size_t)z * SEQ * SEQ;  // E bf16
    float* lsum = (float*)Out1;
    float rs[4][4];
#pragma unroll
    for (int i = 0; i < 4; i++)
#pragma unroll
      for (int r = 0; r < 4; r++) rs[i][r] = 0.f;
#pragma unroll
    for (int j = 0; j < 4; j++) {
      const int gc = bncol + wc * 64 + j * 16 + lcol;
#pragma unroll
      for (int i = 0; i < 4; i++) {
        const int grow = bm + wr * 64 + i * 16 + lrow;
        unsigned short* o = Oz + (size_t)grow * SEQ + gc;
#pragma unroll
        for (int r = 0; r < 4; r++) {
          const unsigned short eb = f2b(__expf(acc[i][j][r] - EXP_SHIFT));
          o[(size_t)r * SEQ] = eb;
          rs[i][r] += b2f(eb);
        }
      }
    }
    // reduce each row partial across the 16 lanes of this g-group, one atomic per row
#pragma unroll
    for (int i = 0; i < 4; i++)
#pragma unroll
      for (int r = 0; r < 4; r++) {
        float s = rs[i][r];
        s += __shfl_xor(s, 1);
        s += __shfl_xor(s, 2);
        s += __shfl_xor(s, 4);
        s += __shfl_xor(s, 8);
        if ((lane & 15) == 0)
          atomicAdd(lsum + (size_t)z * SEQ + bm + wr * 64 + i * 16 + lrow + r, s);
      }
  } else {
    const float* lsum = bias0;
    float invl[4][4];
#pragma unroll
    for (int i = 0; i < 4; i++)
#pragma unroll
      for (int r = 0; r < 4; r++)
        invl[i][r] = 1.0f / lsum[(size_t)z * SEQ + bm + wr * 64 + i * 16 + lrow + r];
    float* Oz = (float*)Out0 + (size_t)z * SEQ * DIM;
#pragma unroll
    for (int j = 0; j < 4; j++) {
      const int gc = bncol + wc * 64 + j * 16 + lcol;
#pragma unroll
      for (int i = 0; i < 4; i++) {
        const int grow = bm + wr * 64 + i * 16 + lrow;
        float* o = Oz + (size_t)grow * DIM + gc;
        o[0 * DIM] = acc[i][j][0] * invl[i][0];
        o[1 * DIM] = acc[i][j][1] * invl[i][1];
        o[2 * DIM] = acc[i][j][2] * invl[i][2];
        o[3 * DIM] = acc[i][j][3] * invl[i][3];
      }
    }
  }
}

extern "C" void kernel_launch(void* const* d_in, const int* in_sizes, int n_in,
                              void* d_out, int out_size, void* d_ws, size_t ws_size,
                              hipStream_t stream) {
  (void)in_sizes; (void)n_in; (void)out_size;
  const float* x  = (const float*)d_in[0];
  const float* lg = (const float*)d_in[1];
  const float* lb = (const float*)d_in[2];
  const float* wq = (const float*)d_in[3];
  const float* bq = (const float*)d_in[4];
  const float* wk = (const float*)d_in[5];
  const float* bk = (const float*)d_in[6];
  const float* wv = (const float*)d_in[7];
  const float* bv = (const float*)d_in[8];
  float* out = (float*)d_out;

  const size_t MT = (size_t)NB * SEQ;  // 16384 tokens
  f16* xn  = (f16*)d_ws;               // [16384][768] f16
  f16* wc  = xn + MT * DIM;            // [3][768][768] f16
  f16* Q   = wc + (size_t)3 * DIM * DIM;
  f16* Km  = Q + MT * DIM;
  unsigned short* Vt = (unsigned short*)(Km + MT * DIM);  // [8][768][2048] bf16
  float* lsum = (float*)(Vt + MT * DIM);                  // [NB*SEQ] f32, fixed
  char* dyn = (char*)(lsum + MT);
  const size_t used = (size_t)(dyn - (char*)d_ws);
  const size_t per_batch = (size_t)SEQ * SEQ * 2;  // E bf16
  size_t rem = (ws_size > used) ? (ws_size - used) : 0;
  int nbc = (int)(rem / per_batch);
  if (nbc < 1) nbc = 1;
  if (nbc > NB) nbc = NB;
  unsigned short* E = (unsigned short*)dyn;  // [nbc][SEQ][SEQ] bf16

  cvt_w_kernel<<<dim3(3 * DIM * DIM / 1024), 256, 0, stream>>>(wq, wk, wv, wc);
  ln_kernel<<<dim3((unsigned)MT), 256, 0, stream>>>(x, lg, lb, xn);
  hipMemsetAsync(lsum, 0, MT * 4, stream);
  gemm_s<0><<<dim3(128 * 18), 256, 0, stream>>>(xn, wc, Q, Km, Vt, bq, bk, bv, DIM);

  for (int b0 = 0; b0 < NB; b0 += nbc) {
    const int nb = (NB - b0 < nbc) ? (NB - b0) : nbc;
    gemm_s<1><<<dim3(nb * 256), 256, 0, stream>>>(
        Q + (size_t)b0 * SEQ * DIM, Km + (size_t)b0 * SEQ * DIM,
        E, lsum + (size_t)b0 * SEQ, nullptr, nullptr, nullptr, nullptr, DIM);
    gemm_s<2><<<dim3(nb * 96), 256, 0, stream>>>(
        (const f16*)E, (const f16*)(Vt + (size_t)b0 * DIM * SEQ),
        out + (size_t)b0 * SEQ * DIM, nullptr, nullptr, lsum + (size_t)b0 * SEQ,
        nullptr, nullptr, SEQ);
  }
}